// Round 7
// baseline (129.866 us; speedup 1.0000x reference)
//
#include <hip/hip_runtime.h>
#include <math.h>

#define NN 8
#define CC 4
#define FF 257
#define TT 2000
#define BB 8
#define MM 80
#define EPSF 1e-5f
#define VSTR 260   // 16B-aligned rows; bank offset 4/row -> worst 2-way (free)
#define T4N 500    // TT/4

typedef float v2f __attribute__((ext_vector_type(2)));

__device__ __forceinline__ float fsqrt_fast(float x) { return __builtin_amdgcn_sqrtf(x); }
__device__ __forceinline__ float flog_fast(float x)  { return __builtin_amdgcn_logf(x) * 0.69314718055994531f; }
__device__ __forceinline__ v2f sqrt2(v2f m) {
    v2f r; r.x = __builtin_amdgcn_sqrtf(m.x); r.y = __builtin_amdgcn_sqrtf(m.y); return r;
}

// ---------------- kernel 1: beamform q,k and reduce s partials ----------------
__global__ __launch_bounds__(256) void k_beam_s(
    const float* __restrict__ xr_g, const float* __restrict__ xi_g,
    const float* __restrict__ wq_r, const float* __restrict__ wq_i,
    const float* __restrict__ wk_r, const float* __restrict__ wk_i,
    float* __restrict__ s_buf)
{
    int nf = blockIdx.x;
    int n = nf / FF, f = nf % FF;
    int t4 = blockIdx.y * 256 + threadIdx.x;

    float part[BB];
#pragma unroll
    for (int b = 0; b < BB; ++b) part[b] = 0.f;

    if (t4 < T4N) {
        const float* xr_base = xr_g + ((size_t)(n*CC)*FF + f) * TT + t4*4;
        const float* xi_base = xi_g + ((size_t)(n*CC)*FF + f) * TT + t4*4;
        v2f xr2[CC][2], xi2[CC][2];
#pragma unroll
        for (int c = 0; c < CC; ++c) {
            float4 r4 = *reinterpret_cast<const float4*>(xr_base + (size_t)c*FF*TT);
            float4 i4 = *reinterpret_cast<const float4*>(xi_base + (size_t)c*FF*TT);
            xr2[c][0].x = r4.x; xr2[c][0].y = r4.y; xr2[c][1].x = r4.z; xr2[c][1].y = r4.w;
            xi2[c][0].x = i4.x; xi2[c][0].y = i4.y; xi2[c][1].x = i4.z; xi2[c][1].y = i4.w;
        }

        const float4 qr4 = *reinterpret_cast<const float4*>(&wq_r[f*CC]);  // f block-uniform -> s_load
        const float4 qi4 = *reinterpret_cast<const float4*>(&wq_i[f*CC]);

        v2f qq[2];
#pragma unroll
        for (int p = 0; p < 2; ++p) {
            v2f qr = xr2[0][p]*qr4.x + xr2[1][p]*qr4.y + xr2[2][p]*qr4.z + xr2[3][p]*qr4.w
                   - xi2[0][p]*qi4.x - xi2[1][p]*qi4.y - xi2[2][p]*qi4.z - xi2[3][p]*qi4.w;
            v2f qi = xi2[0][p]*qr4.x + xi2[1][p]*qr4.y + xi2[2][p]*qr4.z + xi2[3][p]*qr4.w
                   + xr2[0][p]*qi4.x + xr2[1][p]*qi4.y + xr2[2][p]*qi4.z + xr2[3][p]*qi4.w;
            qq[p] = qr*qr + qi*qi + EPSF;
        }

#pragma unroll
        for (int b = 0; b < BB; ++b) {
            const float4 wr4 = *reinterpret_cast<const float4*>(&wk_r[(f*BB + b)*CC]);
            const float4 wi4 = *reinterpret_cast<const float4*>(&wk_i[(f*BB + b)*CC]);
            v2f acc; acc.x = 0.f; acc.y = 0.f;
#pragma unroll
            for (int p = 0; p < 2; ++p) {
                v2f kr = xr2[0][p]*wr4.x + xr2[1][p]*wr4.y + xr2[2][p]*wr4.z + xr2[3][p]*wr4.w
                       - xi2[0][p]*wi4.x - xi2[1][p]*wi4.y - xi2[2][p]*wi4.z - xi2[3][p]*wi4.w;
                v2f ki = xi2[0][p]*wr4.x + xi2[1][p]*wr4.y + xi2[2][p]*wr4.z + xi2[3][p]*wr4.w
                       + xr2[0][p]*wi4.x + xr2[1][p]*wi4.y + xr2[2][p]*wi4.z + xr2[3][p]*wi4.w;
                v2f kk = kr*kr + ki*ki + EPSF;
                acc += sqrt2(qq[p] * kk);   // sqrt(qq)*sqrt(kk) fused
            }
            part[b] = acc.x + acc.y;
        }
    }

    __shared__ float red[4][BB];
    int lane = threadIdx.x & 63, wv = threadIdx.x >> 6;
#pragma unroll
    for (int b = 0; b < BB; ++b) {
        float v = part[b];
#pragma unroll
        for (int m = 32; m >= 1; m >>= 1) v += __shfl_xor(v, m);
        if (lane == 0) red[wv][b] = v;
    }
    __syncthreads();
    if (threadIdx.x < BB) {
        float v = red[0][threadIdx.x] + red[1][threadIdx.x]
                + red[2][threadIdx.x] + red[3][threadIdx.x];
        int bin = (blockIdx.x * 2 + blockIdx.y) & 15;
        atomicAdd(&s_buf[bin*64 + n*BB + threadIdx.x], v);
    }
}

// ---------------- kernel 2: softmax over B per n (sums 16 bins) ----------------
__global__ void k_softmax(const float* __restrict__ s_buf, float* __restrict__ w_buf)
{
    int tid = threadIdx.x;
    if (tid < NN*BB) {
        float v = 0.f;
#pragma unroll
        for (int j = 0; j < 16; ++j) v += s_buf[j*64 + tid];
        v *= (1.0f / TT);
        float mx = v;
#pragma unroll
        for (int m = 4; m >= 1; m >>= 1) mx = fmaxf(mx, __shfl_xor(mx, m));
        float e = expf(v - mx);
        float sm = e;
#pragma unroll
        for (int m = 4; m >= 1; m >>= 1) sm += __shfl_xor(sm, m);
        w_buf[tid] = e / sm;
    }
}

// ---------------- kernel 2b: repack proj_w into padded stride-260 ----------------
__global__ void k_prep(const float* __restrict__ proj_w, float* __restrict__ proj_pad)
{
    int i = blockIdx.x * 256 + threadIdx.x;
    if (i < MM * 260) {
        int m = i / 260, f = i % 260;
        proj_pad[i] = (f < FF) ? proj_w[m*FF + f] : 0.f;
    }
}

// ======== fused kernel helpers ========

// issue half-tile x loads (k-iters k0, k0+1) into registers
__device__ __forceinline__ void load_half(
    const float* __restrict__ xr_g, const float* __restrict__ xi_g,
    int n, int t0, int t4s, int fbase, int k0,
    float4 (&r)[2][CC], float4 (&im)[2][CC])
{
#pragma unroll
    for (int kk = 0; kk < 2; ++kk) {
        int f = fbase + 64*(k0 + kk);
#pragma unroll
        for (int c = 0; c < CC; ++c) {
            size_t base = ((size_t)(n*CC + c)*FF + f)*TT + t0 + t4s*4;
            r[kk][c]  = *reinterpret_cast<const float4*>(xr_g + base);
            im[kk][c] = *reinterpret_cast<const float4*>(xi_g + base);
        }
    }
}

// beamform the half-tile held in registers and store into LDS
__device__ __forceinline__ void fill_half(
    float* v_lds,
    const float* __restrict__ wv_r, const float* __restrict__ wv_i,
    const float (&wn)[BB], int t4s, int fbase, int k0,
    const float4 (&r)[2][CC], const float4 (&im)[2][CC])
{
#pragma unroll
    for (int kk = 0; kk < 2; ++kk) {
        int f = fbase + 64*(k0 + kk);
        v2f xr2[CC][2], xi2[CC][2];
#pragma unroll
        for (int c = 0; c < CC; ++c) {
            xr2[c][0].x = r[kk][c].x;  xr2[c][0].y = r[kk][c].y;
            xr2[c][1].x = r[kk][c].z;  xr2[c][1].y = r[kk][c].w;
            xi2[c][0].x = im[kk][c].x; xi2[c][0].y = im[kk][c].y;
            xi2[c][1].x = im[kk][c].z; xi2[c][1].y = im[kk][c].w;
        }
        v2f vo[2];
        vo[0].x = 0.f; vo[0].y = 0.f; vo[1].x = 0.f; vo[1].y = 0.f;
#pragma unroll
        for (int b = 0; b < BB; ++b) {
            const float4 wr4 = *reinterpret_cast<const float4*>(&wv_r[(f*BB + b)*CC]);
            const float4 wi4 = *reinterpret_cast<const float4*>(&wv_i[(f*BB + b)*CC]);
#pragma unroll
            for (int p = 0; p < 2; ++p) {
                v2f vr = xr2[0][p]*wr4.x + xr2[1][p]*wr4.y + xr2[2][p]*wr4.z + xr2[3][p]*wr4.w
                       - xi2[0][p]*wi4.x - xi2[1][p]*wi4.y - xi2[2][p]*wi4.z - xi2[3][p]*wi4.w;
                v2f vi = xi2[0][p]*wr4.x + xi2[1][p]*wr4.y + xi2[2][p]*wr4.z + xi2[3][p]*wr4.w
                       + xr2[0][p]*wi4.x + xr2[1][p]*wi4.y + xr2[2][p]*wi4.z + xr2[3][p]*wi4.w;
                vo[p] += wn[b] * sqrt2(vr*vr + vi*vi + EPSF);
            }
        }
        v_lds[(t4s*4 + 0)*VSTR + f] = vo[0].x;
        v_lds[(t4s*4 + 1)*VSTR + f] = vo[0].y;
        v_lds[(t4s*4 + 2)*VSTR + f] = vo[1].x;
        v_lds[(t4s*4 + 3)*VSTR + f] = vo[1].y;
    }
}

// f=256 column: 16 lanes load one t each (call under tid<16)
__device__ __forceinline__ void load_f256(
    const float* __restrict__ xr_g, const float* __restrict__ xi_g,
    int n, int t0, int tid, float (&xr)[CC], float (&xi)[CC])
{
#pragma unroll
    for (int c = 0; c < CC; ++c) {
        size_t base = ((size_t)(n*CC + c)*FF + 256)*TT + t0 + tid;
        xr[c] = xr_g[base];
        xi[c] = xi_g[base];
    }
}

__device__ __forceinline__ void fill_f256(
    float* v_lds, const float* __restrict__ wv_r, const float* __restrict__ wv_i,
    const float (&wn)[BB], int tid, const float (&xr)[CC], const float (&xi)[CC])
{
    float v = 0.f;
#pragma unroll
    for (int b = 0; b < BB; ++b) {
        const float4 wr4 = *reinterpret_cast<const float4*>(&wv_r[(256*BB + b)*CC]);
        const float4 wi4 = *reinterpret_cast<const float4*>(&wv_i[(256*BB + b)*CC]);
        float vr = xr[0]*wr4.x + xr[1]*wr4.y + xr[2]*wr4.z + xr[3]*wr4.w
                 - xi[0]*wi4.x - xi[1]*wi4.y - xi[2]*wi4.z - xi[3]*wi4.w;
        float vi = xi[0]*wr4.x + xi[1]*wr4.y + xi[2]*wr4.z + xi[3]*wr4.w
                 + xr[0]*wi4.x + xr[1]*wi4.y + xr[2]*wi4.z + xr[3]*wi4.w;
        v += wn[b] * fsqrt_fast(vr*vr + vi*vi + EPSF);
    }
    v_lds[tid*VSTR + 256] = v;
}

// projection + relu + log + BN partials for one 16-t tile in LDS
__device__ __forceinline__ void proj_stage(
    const float* v_lds, const float* __restrict__ proj_pad,
    float* __restrict__ out, double* __restrict__ bn_sum, double* __restrict__ bn_sumsq,
    int n, int t0, int bin, int tid)
{
    int tl = tid & 15, fg = tid >> 4;
    v2f acc2[5];
#pragma unroll
    for (int j = 0; j < 5; ++j) { acc2[j].x = 0.f; acc2[j].y = 0.f; }
    const float* pp = proj_pad + fg * 5 * 260;
#pragma unroll 4
    for (int f4 = 0; f4 < 260; f4 += 4) {
        float4 vv = *reinterpret_cast<const float4*>(&v_lds[tl*VSTR + f4]);
        v2f v0, v1;
        v0.x = vv.x; v0.y = vv.y; v1.x = vv.z; v1.y = vv.w;
#pragma unroll
        for (int j = 0; j < 5; ++j) {
            float4 p = *reinterpret_cast<const float4*>(&pp[j*260 + f4]);
            v2f p0, p1; p0.x = p.x; p0.y = p.y; p1.x = p.z; p1.y = p.w;
            acc2[j] += v0*p0 + v1*p1;
        }
    }

    int t = t0 + tl;
#pragma unroll
    for (int j = 0; j < 5; ++j) {
        int m = fg*5 + j;
        float r = flog_fast(fmaxf(acc2[j].x + acc2[j].y, 0.f) + EPSF);
        float s1 = r, s2 = r*r;
#pragma unroll
        for (int msk = 8; msk >= 1; msk >>= 1) {
            s1 += __shfl_xor(s1, msk);
            s2 += __shfl_xor(s2, msk);
        }
        out[((size_t)n*TT + t)*MM + m] = r;
        if (tl == 0) {
            atomicAdd(&bn_sum[bin*MM + m], (double)s1);
            atomicAdd(&bn_sumsq[bin*MM + m], (double)s2);
        }
    }
}

// ---------------- kernel 3 (FUSED, 2-chunk pipelined): ----------------
// grid (NN, 63), block 256. Each block: chunks c0=2*by, c1=c0+1 (c1 skipped when by==62).
// Double-buffered LDS; chunk B's x-loads issue before proj(A) so latency hides under VALU.
__global__ __launch_bounds__(256) void k_vproj(
    const float* __restrict__ xr_g, const float* __restrict__ xi_g,
    const float* __restrict__ wv_r, const float* __restrict__ wv_i,
    const float* __restrict__ w_buf, const float* __restrict__ proj_pad,
    float* __restrict__ out, double* __restrict__ bn_sum, double* __restrict__ bn_sumsq)
{
    __shared__ float v_lds[2][16 * VSTR];
    int n = blockIdx.x;
    int c0 = blockIdx.y * 2;
    int c1 = c0 + 1;
    bool hasB = (c1 < 125);
    int t0A = c0 * 16, t0B = c1 * 16;
    int tid = threadIdx.x;
    int t4s = tid & 3;      // which float4 of the 16-t tile
    int fbase = tid >> 2;   // 0..63

    float wn[BB];
#pragma unroll
    for (int b = 0; b < BB; ++b) wn[b] = w_buf[n*BB + b];   // n uniform -> scalar

    // zero pad columns f=257..259 in both buffers
    if (tid < 64 && (tid & 3) < 3) {
        int t = tid >> 2, f = FF + (tid & 3);
        v_lds[0][t*VSTR + f] = 0.f;
        v_lds[1][t*VSTR + f] = 0.f;
    }

    // ---- chunk A: load + fill ----
    float4 r0[2][CC], i0[2][CC], r1[2][CC], i1[2][CC];
    float xr256[CC], xi256[CC];
    load_half(xr_g, xi_g, n, t0A, t4s, fbase, 0, r0, i0);
    load_half(xr_g, xi_g, n, t0A, t4s, fbase, 2, r1, i1);
    if (tid < 16) load_f256(xr_g, xi_g, n, t0A, tid, xr256, xi256);

    fill_half(v_lds[0], wv_r, wv_i, wn, t4s, fbase, 0, r0, i0);
    fill_half(v_lds[0], wv_r, wv_i, wn, t4s, fbase, 2, r1, i1);
    if (tid < 16) fill_f256(v_lds[0], wv_r, wv_i, wn, tid, xr256, xi256);
    __syncthreads();

    // ---- issue chunk B's first-half loads BEFORE proj(A); pin with clobber ----
    if (hasB) {
        load_half(xr_g, xi_g, n, t0B, t4s, fbase, 0, r0, i0);
        if (tid < 16) load_f256(xr_g, xi_g, n, t0B, tid, xr256, xi256);
    }
    asm volatile("" ::: "memory");

    proj_stage(v_lds[0], proj_pad, out, bn_sum, bn_sumsq, n, t0A, c0 & 15, tid);

    if (hasB) {
        // second-half loads land under first-half fill compute
        load_half(xr_g, xi_g, n, t0B, t4s, fbase, 2, r1, i1);
        fill_half(v_lds[1], wv_r, wv_i, wn, t4s, fbase, 0, r0, i0);
        fill_half(v_lds[1], wv_r, wv_i, wn, t4s, fbase, 2, r1, i1);
        if (tid < 16) fill_f256(v_lds[1], wv_r, wv_i, wn, tid, xr256, xi256);
        __syncthreads();
        proj_stage(v_lds[1], proj_pad, out, bn_sum, bn_sumsq, n, t0B, c1 & 15, tid);
    }
}

// ---------------- kernel 4a: BN finalize (sums 16 bins) ----------------
__global__ void k_bnprep(const double* __restrict__ bn_sum, const double* __restrict__ bn_sumsq,
                         const float* __restrict__ gamma, const float* __restrict__ beta,
                         float* __restrict__ scale, float* __restrict__ shift)
{
    int m = threadIdx.x;
    if (m < MM) {
        double s = 0.0, q = 0.0;
#pragma unroll
        for (int j = 0; j < 16; ++j) { s += bn_sum[j*MM + m]; q += bn_sumsq[j*MM + m]; }
        double inv = 1.0 / (double)(NN * TT);
        double mu = s * inv;
        double var = q * inv - mu * mu;
        float sc = gamma[m] * rsqrtf((float)var + EPSF);
        scale[m] = sc;
        shift[m] = beta[m] - (float)mu * sc;
    }
}

// ---------------- kernel 4b: BN apply in-place (float4) ----------------
__global__ __launch_bounds__(256) void k_bnapply(float* __restrict__ out,
                                                 const float* __restrict__ scale,
                                                 const float* __restrict__ shift)
{
    int i4 = blockIdx.x * 256 + threadIdx.x;
    if (i4 < NN*TT*MM/4) {
        float4 v = *reinterpret_cast<const float4*>(&out[i4*4]);
        int m = (i4*4) % MM;
        v.x = v.x*scale[m+0] + shift[m+0];
        v.y = v.y*scale[m+1] + shift[m+1];
        v.z = v.z*scale[m+2] + shift[m+2];
        v.w = v.w*scale[m+3] + shift[m+3];
        *reinterpret_cast<float4*>(&out[i4*4]) = v;
    }
}

extern "C" void kernel_launch(void* const* d_in, const int* in_sizes, int n_in,
                              void* d_out, int out_size, void* d_ws, size_t ws_size,
                              hipStream_t stream)
{
    const float* x_real   = (const float*)d_in[0];
    const float* x_imag   = (const float*)d_in[1];
    const float* wq_r     = (const float*)d_in[2];
    const float* wq_i     = (const float*)d_in[3];
    const float* wk_r     = (const float*)d_in[4];
    const float* wk_i     = (const float*)d_in[5];
    const float* wv_r     = (const float*)d_in[6];
    const float* wv_i     = (const float*)d_in[7];
    const float* proj_w   = (const float*)d_in[8];
    const float* bn_gamma = (const float*)d_in[9];
    const float* bn_beta  = (const float*)d_in[10];
    float* out = (float*)d_out;

    char* ws = (char*)d_ws;
    float*  s_buf    = (float*)(ws + 0);        // 16 bins x 64 floats (4096 B)
    float*  w_buf    = (float*)(ws + 4096);     // 64 floats
    float*  scale    = (float*)(ws + 4352);     // 80 floats
    float*  shift    = (float*)(ws + 4672);     // 80 floats
    double* bn_sum   = (double*)(ws + 8192);    // 16 bins x 80 doubles (10240 B)
    double* bn_sumsq = (double*)(ws + 18432);   // 16 bins x 80 doubles (10240 B)
    float*  proj_pad = (float*)(ws + 28672);    // 80*260 floats (83200 B)

    hipMemsetAsync(d_ws, 0, 28672, stream);     // zero s_buf + bn bins

    k_prep<<<(MM*260 + 255)/256, 256, 0, stream>>>(proj_w, proj_pad);

    dim3 g1(NN*FF, 2);
    k_beam_s<<<g1, 256, 0, stream>>>(x_real, x_imag, wq_r, wq_i, wk_r, wk_i, s_buf);

    k_softmax<<<1, 64, 0, stream>>>(s_buf, w_buf);

    dim3 g3(NN, 63);
    k_vproj<<<g3, 256, 0, stream>>>(x_real, x_imag, wv_r, wv_i, w_buf, proj_pad,
                                    out, bn_sum, bn_sumsq);

    k_bnprep<<<1, 128, 0, stream>>>(bn_sum, bn_sumsq, bn_gamma, bn_beta, scale, shift);

    k_bnapply<<<(NN*TT*MM/4 + 255)/256, 256, 0, stream>>>(out, scale, shift);
}